// Round 18
// baseline (6125.047 us; speedup 1.0000x reference)
//
#include <hip/hip_runtime.h>

#define Bb 256
#define Ll 1024
#define Gg 16        // batch rows per WG; grid = 16
#define CH 4         // x/dt/mask chunk steps (double-buffered)

typedef _Float16 f16x8 __attribute__((ext_vector_type(8)));
typedef _Float16 f16x4 __attribute__((ext_vector_type(4)));
typedef float f32x4 __attribute__((ext_vector_type(4)));

__device__ __forceinline__ f32x4 MFMA(f16x8 a, f16x8 b, f32x4 c) {
  return __builtin_amdgcn_mfma_f32_16x16x32_f16(a, b, c, 0, 0, 0);
}
__device__ __forceinline__ float fast_tanh(float x) {
  float e = __expf(2.0f * x);
  return 1.0f - 2.0f / (e + 1.0f);
}
__device__ __forceinline__ float fast_sigmoid(float x) {
  return 1.0f / (1.0f + __expf(-x));
}
__device__ __forceinline__ f16x8 ld8(const float* __restrict__ p) {
  const float4 a = *(const float4*)p;
  const float4 c = *(const float4*)(p + 4);
  f16x8 v;
  v[0]=(_Float16)a.x; v[1]=(_Float16)a.y; v[2]=(_Float16)a.z; v[3]=(_Float16)a.w;
  v[4]=(_Float16)c.x; v[5]=(_Float16)c.y; v[6]=(_Float16)c.z; v[7]=(_Float16)c.w;
  return v;
}
// B-fragment from [16 b][128 k] f16 state buffer, granule-XOR swizzle (r16-verified)
__device__ __forceinline__ f16x8 bfrag(const _Float16* __restrict__ buf, int b, int lg, int kt) {
  return *(const f16x8*)&buf[(b << 7) + ((((kt << 2) + lg) ^ b) << 3)];
}
// store lane's 4 D-values (one j-granule) as f16, single b64 (r16-verified)
__device__ __forceinline__ void st4(_Float16* __restrict__ buf, int b, int g, int sub, f32x4 v) {
  f16x4 h;
  h[0]=(_Float16)v[0]; h[1]=(_Float16)v[1]; h[2]=(_Float16)v[2]; h[3]=(_Float16)v[3];
  *(f16x4*)&buf[(b << 7) + ((g ^ b) << 3) + (sub << 2)] = h;
}

// ---------------- prepass: M = W1·W2, N_g = Whh_g·W2, c = W1·b2, d_g = Whh_g·b2 ----------------
// ws layout (floats): [0,16384) M ; [16384,65536) N (384x128) ; [65536,65664) c ; [65664,66048) d
__global__ __launch_bounds__(256) void k_prep(
    const float* __restrict__ W1, const float* __restrict__ W2,
    const float* __restrict__ Whh, const float* __restrict__ b2,
    float* __restrict__ ws)
{
  const int idx = blockIdx.x * 256 + threadIdx.x;
  if (idx < 16384) {
    const int i = idx >> 7, j = idx & 127;
    float s = 0.f;
    for (int k = 0; k < 128; ++k) s = fmaf(W1[i * 128 + k], W2[k * 128 + j], s);
    ws[idx] = s;
  } else if (idx < 65536) {
    const int e = idx - 16384;
    const int r = e >> 7, j = e & 127;
    float s = 0.f;
    for (int k = 0; k < 128; ++k) s = fmaf(Whh[r * 128 + k], W2[k * 128 + j], s);
    ws[idx] = s;
  } else if (idx < 65664) {
    const int i = idx - 65536;
    float s = 0.f;
    for (int k = 0; k < 128; ++k) s = fmaf(W1[i * 128 + k], b2[k], s);
    ws[idx] = s;
  } else if (idx < 66048) {
    const int r = idx - 65664;
    float s = 0.f;
    for (int k = 0; k < 128; ++k) s = fmaf(Whh[r * 128 + k], b2[k], s);
    ws[idx] = s;
  }
}

__global__ __launch_bounds__(512, 1) void k_fused(
    const float* __restrict__ x, const float* __restrict__ dtp,
    const int* __restrict__ mask,
    const float* __restrict__ Wx, const float* __restrict__ bx,
    const float* __restrict__ W1, const float* __restrict__ b1,
    const float* __restrict__ W2, const float* __restrict__ b2,
    const float* __restrict__ Wih, const float* __restrict__ bih,
    const float* __restrict__ Whh, const float* __restrict__ bhh,
    const float* __restrict__ lng, const float* __restrict__ lnb,
    const float* __restrict__ Whd, const float* __restrict__ bhp,
    const float* __restrict__ ws,
    float* __restrict__ out)
{
  const float* Mf32 = ws;
  const float* Nf32 = ws + 16384;
  const float* cf   = ws + 65536;
  const float* df   = ws + 65664;

  const int b0 = blockIdx.x * Gg;
  const int tid = threadIdx.x;
  const int lane = tid & 63;
  const int w = tid >> 6;                   // 0..7
  const int b = lane & 15;                  // batch col
  const int lg = lane >> 4;                 // 0..3
  const int jrow0 = (w << 4) + (lg << 2);   // j = jrow0 + r
  const int g = (w << 1) + (lg >> 1);       // j granule
  const int sub = lg & 1;
  const int arow = (w << 4) + b;            // A-fragment row
  const int koff = lg << 3;

  __shared__ _Float16 n_s[384 * 128];            // 96 KB, A-swizzled (N matrices)
  __shared__ _Float16 xch[2][CH][Gg * 64];       // 16 KB
  __shared__ _Float16 hbuf[2][Gg * 128];         // 8 KB
  __shared__ _Float16 ubuf[2][Gg * 128];         // 8 KB
  __shared__ _Float16 usumb[Gg * 128];           // 4 KB
  __shared__ _Float16 xebuf[Gg * 128];           // 4 KB
  __shared__ float dtm_s[2][CH][Gg];
  __shared__ int   mfl_s[2][CH][Gg];
  __shared__ float lnp[8][3][Gg];
  __shared__ unsigned actb[32];
  __shared__ float cb[1280];                     // b1|b2|bx|bih|bhh|gw
  __shared__ float cvb[128];                     // c = W1·b2
  __shared__ float ddb[384];                     // d_g = Whh_g·b2
  __shared__ float cc[2];

  if (tid < 32) actb[tid] = 0u;
  __syncthreads();
  for (int t0 = tid; t0 < Ll; t0 += 512) {
    int a = 0;
#pragma unroll 8
    for (int bb = 0; bb < Bb; ++bb) a |= mask[(size_t)bb * Ll + t0];
    if (a) atomicOr(&actb[t0 >> 5], 1u << (t0 & 31));
  }
  // ---- N -> LDS (A-fragment granule swizzle; r16/r17-verified pattern) ----
  for (int idx = tid; idx < 384 * 128; idx += 512) {
    const int r = idx >> 7, k = idx & 127;
    n_s[(r << 7) + (((k >> 3) ^ (r & 15)) << 3) + (k & 7)] = (_Float16)Nf32[idx];
  }
  for (int i = tid; i < 128; i += 512) {
    cb[i] = b1[i]; cb[128 + i] = b2[i]; cb[256 + i] = bx[i];
    cb[1152 + i] = lng[i] * Whd[i];
    cvb[i] = cf[i];
  }
  for (int i = tid; i < 384; i += 512) {
    cb[384 + i] = bih[i]; cb[768 + i] = bhh[i]; ddb[i] = df[i];
  }
  if (tid == 0) {
    float s1 = 0.f, s0 = 0.f;
    for (int i = 0; i < 128; ++i) { s1 += lng[i] * Whd[i]; s0 += lnb[i] * Whd[i]; }
    cc[0] = s1; cc[1] = s0 + bhp[0];
  }
  for (int i = tid; i < Gg * 128; i += 512) {
    hbuf[0][i] = (_Float16)0.f; hbuf[1][i] = (_Float16)0.f;
  }
  // ---- chunk 0 ----
  {
    const int ts = tid >> 7, bb = (tid >> 3) & 15, gr = tid & 7;
    const f16x8 v = ld8(x + ((size_t)(b0 + bb) * Ll + ts) * 64 + gr * 8);
    *(f16x8*)&xch[0][ts][(bb << 6) + ((gr ^ (bb & 7)) << 3)] = v;
    if (tid < CH * Gg) {
      const int ts2 = tid >> 4, bb2 = tid & 15;
      const float dv = dtp[(size_t)(b0 + bb2) * Ll + ts2];
      const int mv = mask[(size_t)(b0 + bb2) * Ll + ts2];
      dtm_s[0][ts2][bb2] = dv * (float)mv * 0.25f;
      mfl_s[0][ts2][bb2] = mv;
    }
  }
  // ---- register-stationary A-fragments: W1, M, Wx (40 u32) ----
  f16x8 w1f[4], mf[4], wxf2[2];
#pragma unroll
  for (int kt = 0; kt < 4; ++kt) {
    w1f[kt] = ld8(W1 + (size_t)arow * 128 + kt * 32 + koff);
    mf[kt]  = ld8(Mf32 + (size_t)arow * 128 + kt * 32 + koff);
  }
#pragma unroll
  for (int kt = 0; kt < 2; ++kt)
    wxf2[kt] = ld8(Wx + (size_t)arow * 64 + kt * 32 + koff);

  float hreg[4] = {0.f, 0.f, 0.f, 0.f};
  f32x4 gi_cur[3], gi_nxt[3];
#pragma unroll
  for (int q = 0; q < 3; ++q) { gi_cur[q] = {0,0,0,0}; gi_nxt[q] = {0,0,0,0}; }
  float accb = 0.f, cntb = 0.f;
  int mreg = 0;
  // refill hold regs
  float4 rx0 = {0,0,0,0}, rx1 = {0,0,0,0};
  float rdt = 0.f; int rmk = 0;
  __syncthreads();

  // ---- prologue: xe(0) then gi(0) ----
  {
    f32x4 acc = {0,0,0,0};
#pragma unroll
    for (int kt = 0; kt < 2; ++kt) {
      const f16x8 xv = *(const f16x8*)&xch[0][0][(b << 6) + ((((kt << 2) + lg) ^ (b & 7)) << 3)];
      acc = MFMA(wxf2[kt], xv, acc);
    }
    f32x4 xx;
#pragma unroll
    for (int r = 0; r < 4; ++r) xx[r] = fmaxf(acc[r] + cb[256 + jrow0 + r], 0.f);
    st4(xebuf, b, g, sub, xx);
  }
  __syncthreads();
#pragma unroll
  for (int q = 0; q < 3; ++q) {
    f32x4 ga = {0,0,0,0};
#pragma unroll
    for (int kt = 0; kt < 4; ++kt) {
      const f16x8 a8 = ld8(Wih + (size_t)(q * 128 + arow) * 128 + kt * 32 + koff);
      ga = MFMA(a8, bfrag(xebuf, b, lg, kt), ga);
    }
#pragma unroll
    for (int r = 0; r < 4; ++r) gi_cur[q][r] = ga[r] + cb[384 + q * 128 + jrow0 + r];
  }
  __syncthreads();

#pragma unroll 1
  for (int t = 0; t < Ll; ++t) {
    const int cbuf = (t >> 2) & 1, tc = t & 3;
    const int par = t & 1;
    const float sv = dtm_s[cbuf][tc][b];
    const _Float16* hb = hbuf[par];

    f32x4 vreg, usum;

    // ================= P1: v0 = W1·h ; u0 ; xe(t+1) ; logit(t-1) ; refill-issue =================
    {
      // refill issue (raw loads held in regs; converted+written in P5)
      if (tc == 2) {
        const int cnext = (t >> 2) + 1;
        if (cnext * CH < Ll) {
          const int ts = tid >> 7, bb = (tid >> 3) & 15, gr = tid & 7;
          const float* sp = x + ((size_t)(b0 + bb) * Ll + cnext * CH + ts) * 64 + gr * 8;
          rx0 = *(const float4*)sp; rx1 = *(const float4*)(sp + 4);
          if (tid < CH * Gg) {
            const int ts2 = tid >> 4, bb2 = tid & 15;
            rdt = dtp[(size_t)(b0 + bb2) * Ll + cnext * CH + ts2];
            rmk = mask[(size_t)(b0 + bb2) * Ll + cnext * CH + ts2];
          }
        }
      }
      f32x4 acc = {0,0,0,0};
#pragma unroll
      for (int kt = 0; kt < 4; ++kt) acc = MFMA(w1f[kt], bfrag(hb, b, lg, kt), acc);
      f32x4 u0;
#pragma unroll
      for (int r = 0; r < 4; ++r) {
        vreg[r] = acc[r];
        u0[r] = fast_tanh(vreg[r] + cb[jrow0 + r]);
        usum[r] = u0[r];
      }
      st4(ubuf[0], b, g, sub, u0);
      // xe(t+1)
      if (t + 1 < Ll) {
        const int ns = (t + 1) & 3, nb = ((t + 1) >> 2) & 1;
        f32x4 xacc = {0,0,0,0};
#pragma unroll
        for (int kt = 0; kt < 2; ++kt) {
          const f16x8 xv = *(const f16x8*)&xch[nb][ns][(b << 6) + ((((kt << 2) + lg) ^ (b & 7)) << 3)];
          xacc = MFMA(wxf2[kt], xv, xacc);
        }
        f32x4 xx;
#pragma unroll
        for (int r = 0; r < 4; ++r) xx[r] = fmaxf(xacc[r] + cb[256 + jrow0 + r], 0.f);
        st4(xebuf, b, g, sub, xx);
      }
      // logit(t-1)
      if (w == 0 && lane < 16 && t > 0) {
        float S1 = 0.f, S2 = 0.f, SD = 0.f;
#pragma unroll
        for (int q = 0; q < 8; ++q) {
          S1 += lnp[q][0][lane]; S2 += lnp[q][1][lane]; SD += lnp[q][2][lane];
        }
        if (mreg) {
          const float mu = S1 * (1.0f / 128.0f);
          const float var = S2 * (1.0f / 128.0f) - mu * mu;
          const float rstd = rsqrtf(var + 1e-5f);
          accb += rstd * (SD - mu * cc[0]) + cc[1];
          cntb += 1.f;
        }
      }
    }
    __syncthreads();

    f32x4 wh0[3];   // Whh_g · h0

    // ================= P2..P4: v += sv(M·u + c) ; Whh_g·h0 ; gi_g(t+1) =================
#pragma unroll
    for (int s = 0; s < 3; ++s) {
      // stream A-frags from L2 (issued at phase top)
      f16x8 wha[4], wia[4];
#pragma unroll
      for (int kt = 0; kt < 4; ++kt) {
        wha[kt] = ld8(Whh + (size_t)(s * 128 + arow) * 128 + kt * 32 + koff);
        wia[kt] = ld8(Wih + (size_t)(s * 128 + arow) * 128 + kt * 32 + koff);
      }
      f32x4 macc = {0,0,0,0}, ha = {0,0,0,0}, ga = {0,0,0,0};
#pragma unroll
      for (int kt = 0; kt < 4; ++kt) {
        const f16x8 uv = bfrag(ubuf[s & 1], b, lg, kt);
        macc = MFMA(mf[kt], uv, macc);
        ha = MFMA(wha[kt], bfrag(hb, b, lg, kt), ha);
        ga = MFMA(wia[kt], bfrag(xebuf, b, lg, kt), ga);
      }
      wh0[s] = ha;
#pragma unroll
      for (int r = 0; r < 4; ++r) gi_nxt[s][r] = ga[r] + cb[384 + s * 128 + jrow0 + r];
      f32x4 un;
#pragma unroll
      for (int r = 0; r < 4; ++r) {
        vreg[r] = fmaf(sv, macc[r] + cvb[jrow0 + r], vreg[r]);
        un[r] = fast_tanh(vreg[r] + cb[jrow0 + r]);
        usum[r] += un[r];
      }
      if (s < 2) st4(ubuf[(s + 1) & 1], b, g, sub, un);
      else st4(usumb, b, g, sub, usum);   // s==2: u3 folded into usum; write usum
      __syncthreads();
    }

    // ================= P5: 4 matvecs on usum + gates + h_new + LN + refill-write =================
    {
      // W2 A-frags streamed from L2 (issued first)
      f16x8 w2a[4];
#pragma unroll
      for (int kt = 0; kt < 4; ++kt)
        w2a[kt] = ld8(W2 + (size_t)arow * 128 + kt * 32 + koff);
      f32x4 k2 = {0,0,0,0}, kr = {0,0,0,0}, kz = {0,0,0,0}, kn = {0,0,0,0};
#pragma unroll
      for (int kt = 0; kt < 4; ++kt) {
        const f16x8 uv = bfrag(usumb, b, lg, kt);
        k2 = MFMA(w2a[kt], uv, k2);
        const f16x8 nr = *(const f16x8*)&n_s[((size_t)(arow) << 7) + ((((kt << 2) + lg) ^ b) << 3)];
        kr = MFMA(nr, uv, kr);
        const f16x8 nz = *(const f16x8*)&n_s[((size_t)(128 + arow) << 7) + ((((kt << 2) + lg) ^ b) << 3)];
        kz = MFMA(nz, uv, kz);
        const f16x8 nn = *(const f16x8*)&n_s[((size_t)(256 + arow) << 7) + ((((kt << 2) + lg) ^ b) << 3)];
        kn = MFMA(nn, uv, kn);
      }
      const int actv = (actb[t >> 5] >> (t & 31)) & 1;
      const float sv4 = 4.f * sv;
      f32x4 hn;
      float s1 = 0.f, s2 = 0.f, sd = 0.f;
#pragma unroll
      for (int r = 0; r < 4; ++r) {
        const int j = jrow0 + r;
        const float hfin = hreg[r] + sv * k2[r] + sv4 * cb[128 + j];
        const float prer = wh0[0][r] + sv * kr[r] + sv4 * ddb[j] + cb[768 + j];
        const float prez = wh0[1][r] + sv * kz[r] + sv4 * ddb[128 + j] + cb[768 + 128 + j];
        const float pren = wh0[2][r] + sv * kn[r] + sv4 * ddb[256 + j] + cb[768 + 256 + j];
        const float rr = fast_sigmoid(gi_cur[0][r] + prer);
        const float zz = fast_sigmoid(gi_cur[1][r] + prez);
        const float nn = fast_tanh(gi_cur[2][r] + rr * pren);
        const float hg = (1.f - zz) * nn + zz * hfin;
        hreg[r] = actv ? hg : hfin;
        hn[r] = hreg[r];
        s1 += hreg[r]; s2 += hreg[r] * hreg[r]; sd += hreg[r] * cb[1152 + j];
      }
      st4(hbuf[(t + 1) & 1], b, g, sub, hn);
      // LN partials
      s1 += __shfl_xor(s1, 16); s2 += __shfl_xor(s2, 16); sd += __shfl_xor(sd, 16);
      s1 += __shfl_xor(s1, 32); s2 += __shfl_xor(s2, 32); sd += __shfl_xor(sd, 32);
      if (lane < 16) { lnp[w][0][b] = s1; lnp[w][1][b] = s2; lnp[w][2][b] = sd; }
      if (w == 0 && lane < 16) mreg = mfl_s[cbuf][tc][lane];
      // gi rotate
#pragma unroll
      for (int q = 0; q < 3; ++q) gi_cur[q] = gi_nxt[q];
      // refill write (loads issued in P1, ~4 phases ago)
      if (tc == 2) {
        const int cnext = (t >> 2) + 1;
        if (cnext * CH < Ll) {
          const int nb = cnext & 1;
          const int ts = tid >> 7, bb = (tid >> 3) & 15, gr = tid & 7;
          f16x8 v;
          v[0]=(_Float16)rx0.x; v[1]=(_Float16)rx0.y; v[2]=(_Float16)rx0.z; v[3]=(_Float16)rx0.w;
          v[4]=(_Float16)rx1.x; v[5]=(_Float16)rx1.y; v[6]=(_Float16)rx1.z; v[7]=(_Float16)rx1.w;
          *(f16x8*)&xch[nb][ts][(bb << 6) + ((gr ^ (bb & 7)) << 3)] = v;
          if (tid < CH * Gg) {
            const int ts2 = tid >> 4, bb2 = tid & 15;
            dtm_s[nb][ts2][bb2] = rdt * (float)rmk * 0.25f;
            mfl_s[nb][ts2][bb2] = rmk;
          }
        }
      }
    }
    __syncthreads();
  }

  // ---- epilogue: logit for t=1023 ----
  if (w == 0 && lane < 16) {
    float S1 = 0.f, S2 = 0.f, SD = 0.f;
#pragma unroll
    for (int q = 0; q < 8; ++q) {
      S1 += lnp[q][0][lane]; S2 += lnp[q][1][lane]; SD += lnp[q][2][lane];
    }
    if (mreg) {
      const float mu = S1 * (1.0f / 128.0f);
      const float var = S2 * (1.0f / 128.0f) - mu * mu;
      const float rstd = rsqrtf(var + 1e-5f);
      accb += rstd * (SD - mu * cc[0]) + cc[1];
      cntb += 1.f;
    }
    out[b0 + lane] = accb / fmaxf(cntb, 1.f);
  }
}

// ---------------- host ----------------
extern "C" void kernel_launch(void* const* d_in, const int* in_sizes, int n_in,
                              void* d_out, int out_size, void* d_ws, size_t ws_size,
                              hipStream_t stream) {
  const float* x    = (const float*)d_in[0];
  const float* dt   = (const float*)d_in[1];
  const int*   mask = (const int*)d_in[2];
  const float* Wx   = (const float*)d_in[3];
  const float* bx   = (const float*)d_in[4];
  const float* W1   = (const float*)d_in[5];
  const float* b1   = (const float*)d_in[6];
  const float* W2   = (const float*)d_in[7];
  const float* b2   = (const float*)d_in[8];
  const float* Wih  = (const float*)d_in[9];
  const float* bih  = (const float*)d_in[10];
  const float* Whh  = (const float*)d_in[11];
  const float* bhh  = (const float*)d_in[12];
  const float* lng  = (const float*)d_in[13];
  const float* lnb  = (const float*)d_in[14];
  const float* Wh   = (const float*)d_in[15];
  const float* bh   = (const float*)d_in[16];
  float* ws = (float*)d_ws;   // needs 66048 floats = 258.0 KB
  float* out = (float*)d_out;

  k_prep<<<dim3(258), dim3(256), 0, stream>>>(W1, W2, Whh, b2, ws);
  k_fused<<<dim3(Bb / Gg), dim3(512), 0, stream>>>(
      x, dt, mask, Wx, bx, W1, b1, W2, b2, Wih, bih, Whh, bhh,
      lng, lnb, Wh, bh, ws, out);
}

// Round 19
// 2772.770 us; speedup vs baseline: 2.2090x; 2.2090x over previous
//
#include <hip/hip_runtime.h>

#define Bb 256
#define Ll 1024
#define CH 32

typedef _Float16 h2v __attribute__((ext_vector_type(2)));

__device__ __forceinline__ unsigned pack_h2(float a, float b) {
  h2v v; v[0] = (_Float16)a; v[1] = (_Float16)b;
  return __builtin_bit_cast(unsigned, v);
}
__device__ __forceinline__ float dot2(unsigned w, unsigned x, float acc) {
#if defined(__has_builtin) && __has_builtin(__builtin_amdgcn_fdot2)
  return __builtin_amdgcn_fdot2(__builtin_bit_cast(h2v, w),
                                __builtin_bit_cast(h2v, x), acc, false);
#else
  h2v wv = __builtin_bit_cast(h2v, w), xv = __builtin_bit_cast(h2v, x);
  acc = fmaf((float)wv[0], (float)xv[0], acc);
  return fmaf((float)wv[1], (float)xv[1], acc);
#endif
}
__device__ __forceinline__ float dppadd1(float v) {   // + lane^1
  int s = __builtin_amdgcn_mov_dpp(__builtin_bit_cast(int, v), 0xB1, 0xF, 0xF, true);
  return v + __builtin_bit_cast(float, s);
}
__device__ __forceinline__ float dppadd2(float v) {   // + lane^2
  int s = __builtin_amdgcn_mov_dpp(__builtin_bit_cast(int, v), 0x4E, 0xF, 0xF, true);
  return v + __builtin_bit_cast(float, s);
}
__device__ __forceinline__ float qsum(float a0, float a1) {
  return dppadd2(dppadd1(a0 + a1));   // sum across the 4-lane quad (quad-uniform)
}
__device__ __forceinline__ float fast_tanh(float x) {
  float e = __expf(2.0f * x);
  return 1.0f - 2.0f / (e + 1.0f);
}
__device__ __forceinline__ float fast_sigmoid(float x) {
  return 1.0f / (1.0f + __expf(-x));
}

// 32-wide K-slice matvec: 16 dot2, 2 chains, quad reduce (result quad-uniform)
__device__ __forceinline__ float mv16(const unsigned* __restrict__ w,
                                      const unsigned* __restrict__ v, int q0) {
  float a0 = 0.0f, a1 = 0.0f;
#pragma unroll
  for (int c = 0; c < 4; ++c) {
    const uint4 hv = *(const uint4*)&v[q0 + 4 * c];
    a0 = dot2(w[4*c+0], hv.x, a0); a1 = dot2(w[4*c+1], hv.y, a1);
    a0 = dot2(w[4*c+2], hv.z, a0); a1 = dot2(w[4*c+3], hv.w, a1);
  }
  return qsum(a0, a1);
}
// matvec with LDS-resident XOR-swizzled weight row (r12-verified)
__device__ __forceinline__ float giq(const unsigned* __restrict__ wrow,
                                     const unsigned* __restrict__ xe,
                                     int q0, int swi) {
  float g0 = 0.0f, g1 = 0.0f;
#pragma unroll
  for (int c = 0; c < 4; ++c) {
    const uint4 xv = *(const uint4*)&xe[q0 + 4 * c];
    const uint4 w4 = *(const uint4*)&wrow[(q0 + 4 * c) ^ swi];
    g0 = dot2(w4.x, xv.x, g0); g1 = dot2(w4.y, xv.y, g1);
    g0 = dot2(w4.z, xv.z, g0); g1 = dot2(w4.w, xv.w, g1);
  }
  return qsum(g0, g1);
}

// ---- prepass: M = W1·W2 (16384 f32), c = W1·b2 (128 f32) into ws ----
__global__ __launch_bounds__(256) void k_prep(
    const float* __restrict__ W1, const float* __restrict__ W2,
    const float* __restrict__ b2, float* __restrict__ ws)
{
  const int idx = blockIdx.x * 256 + threadIdx.x;
  if (idx < 16384) {
    const int i = idx >> 7, j = idx & 127;
    float s = 0.f;
    for (int k = 0; k < 128; ++k) s = fmaf(W1[i * 128 + k], W2[k * 128 + j], s);
    ws[idx] = s;
  } else if (idx < 16512) {
    const int i = idx - 16384;
    float s = 0.f;
    for (int k = 0; k < 128; ++k) s = fmaf(W1[i * 128 + k], b2[k], s);
    ws[idx] = s;
  }
}

// One WG (512 thr, 8 waves) per batch row; r12 mapping: j = wv*16 + (lane>>2),
// ks = lane&3 (32-wide K-slice). 6 phases/step via v-chain algebra.
__global__ __launch_bounds__(512, 1) void k_fused(
    const float* __restrict__ x, const float* __restrict__ dtp,
    const int* __restrict__ mask,
    const float* __restrict__ Wx, const float* __restrict__ bx,
    const float* __restrict__ W1, const float* __restrict__ b1,
    const float* __restrict__ W2, const float* __restrict__ b2,
    const float* __restrict__ Wih, const float* __restrict__ bih,
    const float* __restrict__ Whh, const float* __restrict__ bhh,
    const float* __restrict__ lng, const float* __restrict__ lnb,
    const float* __restrict__ Whd, const float* __restrict__ bhp,
    const float* __restrict__ ws,
    float* __restrict__ out)
{
  const float* Mf = ws;
  const float* cf = ws + 16384;

  const int b = blockIdx.x;
  const int tid = threadIdx.x;
  const int lane = tid & 63;
  const int wv = tid >> 6;            // 0..7
  const int jl = lane >> 2;           // 0..15
  const int ks = lane & 3;            // 0..3
  const int j = (wv << 4) + jl;       // 0..127
  const int q0 = ks << 4;             // u32 base in 64-u32 (K=128) arrays
  const int q0x = ks << 3;            // u32 base in 32-u32 (F=64) rows
  const int swi = (j & 15) << 2;

  __shared__ int act_lds[Ll];                               // 4 KB
  __shared__ __align__(16) unsigned wih_lds[3 * 128 * 64];  // 96 KB, swizzled
  __shared__ __align__(16) unsigned w2_lds[128 * 64];       // 32 KB, swizzled
  __shared__ __align__(16) unsigned x16[2][CH * 32];        // 8 KB (dbuf)
  __shared__ __align__(16) unsigned xe16[64];
  __shared__ __align__(16) unsigned ubuf[2][64];
  __shared__ __align__(16) unsigned usumb[64];
  __shared__ __align__(16) unsigned fb16[64];
  __shared__ __align__(16) unsigned h16[2][64];
  __shared__ float dt_ch[2][CH];
  __shared__ int   m_ch[2][CH];
  __shared__ float red_lds[48];
  __shared__ float cc_lds[2];

  // ---- act prepass (coalesced) ----
  for (int t0 = tid; t0 < Ll; t0 += 512) {
    int a = 0;
#pragma unroll 8
    for (int bb = 0; bb < Bb; ++bb) a |= mask[(size_t)bb * Ll + t0];
    act_lds[t0] = a;
  }
  // ---- Wih -> LDS f16 pairs, XOR-swizzled (r12-verified) ----
  for (int idx = tid; idx < 3 * 128 * 64; idx += 512) {
    const int r = idx >> 6, w = idx & 63;
    wih_lds[(r << 6) | (w ^ ((r & 15) << 2))] =
        pack_h2(Wih[(size_t)r * 128 + 2 * w], Wih[(size_t)r * 128 + 2 * w + 1]);
  }
  // ---- W2 -> LDS f16 pairs, same swizzle ----
  for (int idx = tid; idx < 128 * 64; idx += 512) {
    const int r = idx >> 6, w = idx & 63;
    w2_lds[(r << 6) | (w ^ ((r & 15) << 2))] =
        pack_h2(W2[(size_t)r * 128 + 2 * w], W2[(size_t)r * 128 + 2 * w + 1]);
  }
  if (tid == 0) {
    float s1 = 0.f, s0 = 0.f;
    for (int i = 0; i < 128; ++i) { s1 += lng[i] * Whd[i]; s0 += lnb[i] * Whd[i]; }
    cc_lds[0] = s1; cc_lds[1] = s0 + bhp[0];
  }
  // ---- chunk 0 (steps 0..31) ----
  {
    const int sl = tid >> 4, part = tid & 15;
    const float4 a = *(const float4*)(x + ((size_t)b * Ll + sl) * 64 + part * 4);
    x16[0][sl * 32 + part * 2 + 0] = pack_h2(a.x, a.y);
    x16[0][sl * 32 + part * 2 + 1] = pack_h2(a.z, a.w);
    if (tid < CH) dt_ch[0][tid] = dtp[(size_t)b * Ll + tid];
    else if (tid < 2 * CH) m_ch[0][tid - CH] = mask[(size_t)b * Ll + (tid - CH)];
  }
  // ---- register-stationary weights (88 u32): W1, M, Whh(x3), Wx ----
  unsigned w1h[16], mh[16], whr[16], whz[16], whn[16], wxh[8];
#pragma unroll
  for (int ii = 0; ii < 8; ++ii) {
    float4 a4;
    a4 = *(const float4*)&W1[(size_t)j * 128 + (ks << 5) + 4 * ii];
    w1h[2*ii] = pack_h2(a4.x, a4.y); w1h[2*ii+1] = pack_h2(a4.z, a4.w);
    a4 = *(const float4*)&Mf[(size_t)j * 128 + (ks << 5) + 4 * ii];
    mh[2*ii] = pack_h2(a4.x, a4.y); mh[2*ii+1] = pack_h2(a4.z, a4.w);
    a4 = *(const float4*)&Whh[(size_t)j * 128 + (ks << 5) + 4 * ii];
    whr[2*ii] = pack_h2(a4.x, a4.y); whr[2*ii+1] = pack_h2(a4.z, a4.w);
    a4 = *(const float4*)&Whh[(size_t)(128 + j) * 128 + (ks << 5) + 4 * ii];
    whz[2*ii] = pack_h2(a4.x, a4.y); whz[2*ii+1] = pack_h2(a4.z, a4.w);
    a4 = *(const float4*)&Whh[(size_t)(256 + j) * 128 + (ks << 5) + 4 * ii];
    whn[2*ii] = pack_h2(a4.x, a4.y); whn[2*ii+1] = pack_h2(a4.z, a4.w);
  }
#pragma unroll
  for (int ii = 0; ii < 4; ++ii) {
    const float4 a4 = *(const float4*)&Wx[(size_t)j * 64 + (ks << 4) + 4 * ii];
    wxh[2*ii] = pack_h2(a4.x, a4.y); wxh[2*ii+1] = pack_h2(a4.z, a4.w);
  }
  const float bxj = bx[j], b1j = b1[j], b2j = b2[j], cj = cf[j];
  const float bir = bih[j], biz = bih[128 + j], bin_ = bih[256 + j];
  const float bhr = bhh[j], bhz = bhh[128 + j], bhn = bhh[256 + j];
  const float gw = lng[j] * Whd[j];

  if (tid < 64) { h16[0][tid] = 0u; h16[1][tid] = 0u; }
  float hreg = 0.f;
  float gicr = 0.f, gicz = 0.f, gicn = 0.f;   // gi(t)
  float gnr = 0.f, gnz = 0.f, gnn = 0.f;      // gi(t+1)
  float accb = 0.f, cntb = 0.f;               // tid==0
  int mreg = 0;
  float4 rx0 = {0,0,0,0}; float rdt = 0.f; int rmk = 0;   // refill hold
  __syncthreads();

  // ---- prologue: xe(0), then gi(0) ----
  {
    float p0 = 0.f, p1 = 0.f;
#pragma unroll
    for (int c = 0; c < 2; ++c) {
      const uint4 xv = *(const uint4*)&x16[0][q0x + 4 * c];
      p0 = dot2(wxh[4*c+0], xv.x, p0); p1 = dot2(wxh[4*c+1], xv.y, p1);
      p0 = dot2(wxh[4*c+2], xv.z, p0); p1 = dot2(wxh[4*c+3], xv.w, p1);
    }
    const float xev = fmaxf(qsum(p0, p1) + bxj, 0.f);
    if (ks == 0) ((_Float16*)xe16)[j] = (_Float16)xev;
  }
  __syncthreads();
  gicr = giq(&wih_lds[j << 6], xe16, q0, swi) + bir;
  gicz = giq(&wih_lds[(128 + j) << 6], xe16, q0, swi) + biz;
  gicn = giq(&wih_lds[(256 + j) << 6], xe16, q0, swi) + bin_;
  __syncthreads();

#pragma unroll 1
  for (int t = 0; t < Ll; ++t) {
    const int cb = (t >> 5) & 1, tc = t & 31;
    const float sv = dt_ch[cb][tc] * (float)m_ch[cb][tc] * 0.25f;
    const unsigned* hb = h16[t & 1];
    const int refill = (tc == 16) && ((t >> 5) < 31);

    float v, usum;

    // ===== P1: v = W1·h ; u0 ; xe(t+1) ; logit(t-1) ; refill-issue =====
    {
      if (refill) {
        const int sl = tid >> 4, part = tid & 15;
        rx0 = *(const float4*)(x + ((size_t)b * Ll + ((t >> 5) + 1) * 32 + sl) * 64 + part * 4);
        if (tid < CH) rdt = dtp[(size_t)b * Ll + ((t >> 5) + 1) * 32 + tid];
        else if (tid < 2 * CH) rmk = mask[(size_t)b * Ll + ((t >> 5) + 1) * 32 + (tid - CH)];
      }
      v = mv16(w1h, hb, q0);
      const float u0 = fast_tanh(v + b1j);
      usum = u0;
      if (ks == 0) ((_Float16*)ubuf[0])[j] = (_Float16)u0;
      if (t + 1 < Ll) {
        const int nb2 = ((t + 1) >> 5) & 1, ns = (t + 1) & 31;
        float p0 = 0.f, p1 = 0.f;
#pragma unroll
        for (int c = 0; c < 2; ++c) {
          const uint4 xv = *(const uint4*)&x16[nb2][ns * 32 + q0x + 4 * c];
          p0 = dot2(wxh[4*c+0], xv.x, p0); p1 = dot2(wxh[4*c+1], xv.y, p1);
          p0 = dot2(wxh[4*c+2], xv.z, p0); p1 = dot2(wxh[4*c+3], xv.w, p1);
        }
        const float xev = fmaxf(qsum(p0, p1) + bxj, 0.f);
        if (ks == 0) ((_Float16*)xe16)[j] = (_Float16)xev;
      }
      if (tid == 0 && t > 0) {
        float S1 = 0.f, S2 = 0.f, SD = 0.f;
#pragma unroll
        for (int q = 0; q < 16; ++q) {
          S1 += red_lds[q * 3 + 0]; S2 += red_lds[q * 3 + 1]; SD += red_lds[q * 3 + 2];
        }
        if (mreg) {
          const float mu = S1 * (1.0f / 128.0f);
          const float var = S2 * (1.0f / 128.0f) - mu * mu;
          const float rstd = rsqrtf(var + 1e-5f);
          accb += rstd * (SD - mu * cc_lds[0]) + cc_lds[1];
          cntb += 1.f;
        }
      }
    }
    __syncthreads();                       // B1

    // ===== P2: v += sv(M·u0 + c) ; u1 ; gi_r(t+1) =====
    {
      const float t2 = mv16(mh, ubuf[0], q0);
      v = fmaf(sv, t2 + cj, v);
      const float u1 = fast_tanh(v + b1j);
      usum += u1;
      if (ks == 0) ((_Float16*)ubuf[1])[j] = (_Float16)u1;
      gnr = giq(&wih_lds[j << 6], xe16, q0, swi) + bir;
    }
    __syncthreads();                       // B2

    // ===== P3: v += sv(M·u1 + c) ; u2 ; gi_z(t+1) =====
    {
      const float t2 = mv16(mh, ubuf[1], q0);
      v = fmaf(sv, t2 + cj, v);
      const float u2 = fast_tanh(v + b1j);
      usum += u2;
      if (ks == 0) ((_Float16*)ubuf[0])[j] = (_Float16)u2;
      gnz = giq(&wih_lds[(128 + j) << 6], xe16, q0, swi) + biz;
    }
    __syncthreads();                       // B3

    // ===== P4: v += sv(M·u2 + c) ; u3 ; usum ; gi_n(t+1) =====
    {
      const float t2 = mv16(mh, ubuf[0], q0);
      v = fmaf(sv, t2 + cj, v);
      const float u3 = fast_tanh(v + b1j);
      usum += u3;
      if (ks == 0) ((_Float16*)usumb)[j] = (_Float16)usum;
      gnn = giq(&wih_lds[(256 + j) << 6], xe16, q0, swi) + bin_;
    }
    __syncthreads();                       // B4

    // ===== P5: h_fin = h0 + sv·W2·usum + 4sv·b2 ; refill-write =====
    float hf;
    {
      const float k2 = giq(&w2_lds[j << 6], usumb, q0, swi);
      hf = hreg + sv * k2 + 4.f * sv * b2j;
      if (ks == 0) ((_Float16*)fb16)[j] = (_Float16)hf;
      if (refill) {
        const int nb = ((t >> 5) + 1) & 1;
        const int sl = tid >> 4, part = tid & 15;
        x16[nb][sl * 32 + part * 2 + 0] = pack_h2(rx0.x, rx0.y);
        x16[nb][sl * 32 + part * 2 + 1] = pack_h2(rx0.z, rx0.w);
        if (tid < CH) dt_ch[nb][tid] = rdt;
        else if (tid < 2 * CH) m_ch[nb][tid - CH] = rmk;
      }
    }
    __syncthreads();                       // B5

    // ===== P6: GRU gates on h_fin ; h_new ; LN partials =====
    {
      const float pr = mv16(whr, fb16, q0) + bhr;
      const float pz = mv16(whz, fb16, q0) + bhz;
      const float pn = mv16(whn, fb16, q0) + bhn;
      const float rr = fast_sigmoid(gicr + pr);
      const float zz = fast_sigmoid(gicz + pz);
      const float nn = fast_tanh(gicn + rr * pn);
      const float hg = (1.f - zz) * nn + zz * hf;
      hreg = act_lds[t] ? hg : hf;
      if (ks == 0) ((_Float16*)h16[(t + 1) & 1])[j] = (_Float16)hreg;
      // LN partials (quad-uniform h[j]): xor 4,8,16 -> 16 slots
      float s1 = hreg, s2 = hreg * hreg, sd = hreg * gw;
#pragma unroll
      for (int o = 4; o <= 16; o <<= 1) {
        s1 += __shfl_xor(s1, o); s2 += __shfl_xor(s2, o); sd += __shfl_xor(sd, o);
      }
      if ((lane & 31) == 0) {
        const int slot = (wv << 1) | (lane >> 5);
        red_lds[slot * 3 + 0] = s1; red_lds[slot * 3 + 1] = s2; red_lds[slot * 3 + 2] = sd;
      }
      if (tid == 0) mreg = m_ch[cb][tc];
      gicr = gnr; gicz = gnz; gicn = gnn;
    }
    __syncthreads();                       // B6
  }

  // ---- epilogue: logit for t=1023 ----
  if (tid == 0) {
    float S1 = 0.f, S2 = 0.f, SD = 0.f;
#pragma unroll
    for (int q = 0; q < 16; ++q) {
      S1 += red_lds[q * 3 + 0]; S2 += red_lds[q * 3 + 1]; SD += red_lds[q * 3 + 2];
    }
    if (mreg) {
      const float mu = S1 * (1.0f / 128.0f);
      const float var = S2 * (1.0f / 128.0f) - mu * mu;
      const float rstd = rsqrtf(var + 1e-5f);
      accb += rstd * (SD - mu * cc_lds[0]) + cc_lds[1];
      cntb += 1.f;
    }
    out[b] = accb / fmaxf(cntb, 1.f);
  }
}

// ---------------- host ----------------
extern "C" void kernel_launch(void* const* d_in, const int* in_sizes, int n_in,
                              void* d_out, int out_size, void* d_ws, size_t ws_size,
                              hipStream_t stream) {
  const float* x    = (const float*)d_in[0];
  const float* dt   = (const float*)d_in[1];
  const int*   mask = (const int*)d_in[2];
  const float* Wx   = (const float*)d_in[3];
  const float* bx   = (const float*)d_in[4];
  const float* W1   = (const float*)d_in[5];
  const float* b1   = (const float*)d_in[6];
  const float* W2   = (const float*)d_in[7];
  const float* b2   = (const float*)d_in[8];
  const float* Wih  = (const float*)d_in[9];
  const float* bih  = (const float*)d_in[10];
  const float* Whh  = (const float*)d_in[11];
  const float* bhh  = (const float*)d_in[12];
  const float* lng  = (const float*)d_in[13];
  const float* lnb  = (const float*)d_in[14];
  const float* Wh   = (const float*)d_in[15];
  const float* bh   = (const float*)d_in[16];
  float* ws = (float*)d_ws;   // needs 16512 floats = 64.5 KB
  float* out = (float*)d_out;

  k_prep<<<dim3(65), dim3(256), 0, stream>>>(W1, W2, b2, ws);
  k_fused<<<dim3(Bb), dim3(512), 0, stream>>>(
      x, dt, mask, Wx, bx, W1, b1, W2, b2, Wih, bih, Whh, bhh,
      lng, lnb, Wh, bh, ws, out);
}